// Round 16
// baseline (3985.924 us; speedup 1.0000x reference)
//
#include <hip/hip_runtime.h>
#include <math.h>

#define Bsz 128
#define Tsz 512
#define Esz 512
#define Hsz 1024
#define G4H 4096
#define Vsz 32000
#define NB  64           // lstm blocks (fat: 512 thr, 16 j-cols each)
#define BH  (Bsz * Hsz)
#define XPS 68           // padded xps row stride (shorts)

typedef __attribute__((ext_vector_type(8))) short short8;
typedef __attribute__((ext_vector_type(4))) short short4v;
typedef __attribute__((ext_vector_type(8))) __bf16 bf16x8;
typedef __attribute__((ext_vector_type(4))) float f32x4;
typedef __attribute__((ext_vector_type(4))) unsigned int uint4v;

__device__ inline unsigned short f2bf(float f) {
    unsigned u = __float_as_uint(f);
    u += 0x7fffu + ((u >> 16) & 1u);   // RTNE
    return (unsigned short)(u >> 16);
}
__device__ inline float bf2f(unsigned short s) {
    return __uint_as_float(((unsigned)s) << 16);
}
__device__ inline f32x4 mfma16(short8 a, short8 b, f32x4 c) {
    return __builtin_amdgcn_mfma_f32_16x16x32_bf16(
        __builtin_bit_cast(bf16x8, a), __builtin_bit_cast(bf16x8, b), c, 0, 0, 0);
}

// async 16B loads; early-clobber so dst never aliases addr regs
#define GLD16P(dst, p)  asm volatile("global_load_dwordx4 %0, %1, off"         : "=&v"(dst) : "v"(p))
#define GLD16C(dst, p)  asm volatile("global_load_dwordx4 %0, %1, off sc0 sc1" : "=&v"(dst) : "v"(p))

#define WAITVM(n)                                                          \
    do { asm volatile("s_waitcnt vmcnt(" #n ")" ::: "memory");             \
         __builtin_amdgcn_sched_barrier(0); } while (0)

// MALL-coherent scalar flag ops (proven R11)
__device__ inline unsigned ld_flag(const unsigned* p) {
    unsigned r;
    asm volatile("global_load_dword %0, %1, off sc0 sc1\n\ts_waitcnt vmcnt(0)"
                 : "=&v"(r) : "v"(p) : "memory");
    return r;
}
__device__ inline void st_flag(unsigned* p, unsigned v) {
    asm volatile("global_store_dword %0, %1, off sc0 sc1" :: "v"(p), "v"(v) : "memory");
}

// ---------------- prep kernels ----------------
__global__ void k_prep_emb(const float* __restrict__ emb, unsigned short* __restrict__ dst) {
    size_t i = (size_t)blockIdx.x * 256 + threadIdx.x;
    if (i < (size_t)Vsz * Esz) dst[i] = f2bf(i < Esz ? 0.f : emb[i]);  // row 0 = PAD -> 0
}

__global__ void k_prep_w(const float* __restrict__ wi, const float* __restrict__ wf,
                         const float* __restrict__ wg, const float* __restrict__ wo,
                         int ncols, unsigned short* __restrict__ dst) {
    size_t i = (size_t)blockIdx.x * 256 + threadIdx.x;
    size_t per = (size_t)Hsz * ncols;
    if (i < 4 * per) {
        int g = (int)(i / per);
        size_t rem = i - (size_t)g * per;
        const float* src = g == 0 ? wi : g == 1 ? wf : g == 2 ? wg : wo;
        dst[i] = f2bf(src[rem]);
    }
}

__global__ void k_prep_misc(const float* __restrict__ bi, const float* __restrict__ bff,
                            const float* __restrict__ bg, const float* __restrict__ bo,
                            float* __restrict__ b4, unsigned short* __restrict__ ghbuf,
                            float* __restrict__ cbuf, float* __restrict__ outh,
                            unsigned* __restrict__ flags) {
    int i = blockIdx.x * 256 + threadIdx.x;
    if (i < G4H) {
        const float* src = i < Hsz ? bi : i < 2 * Hsz ? bff : i < 3 * Hsz ? bg : bo;
        b4[i] = src[i & (Hsz - 1)];
    }
    if (i < 2 * BH) ghbuf[i] = 0;
    if (i < BH) { cbuf[i] = 0.f; outh[i] = 0.f; }
    if (i < NB * 32) flags[i] = 0u;
}

// ---------------- xp = emb[x] @ Wi^T + b  (standalone, chunk-0 prologue) ----------------
__global__ __launch_bounds__(256, 2) void xp_gemm(
    const unsigned short* __restrict__ emb16, const unsigned short* __restrict__ Wi16,
    const float* __restrict__ b4, const int* __restrict__ x,
    unsigned short* __restrict__ xp, int t_base)
{
    const int tp = blockIdx.x;
    const int n0 = blockIdx.y * 128;
    const int tid = threadIdx.x;
    const int w = tid >> 6, l = tid & 63;
    const int wm = w >> 1, wn = w & 1;
    const int lr = l & 15, lk = l >> 4;

    const unsigned short* arow[4];
    #pragma unroll
    for (int mt = 0; mt < 4; ++mt) {
        int b = wm * 64 + mt * 16 + lr;
        int xv = x[b * Tsz + t_base + tp];
        arow[mt] = emb16 + (size_t)xv * Esz + lk * 8;
    }
    const unsigned short* brow[4];
    #pragma unroll
    for (int nt = 0; nt < 4; ++nt) {
        int n = n0 + wn * 64 + nt * 16 + lr;
        brow[nt] = Wi16 + (size_t)n * Esz + lk * 8;
    }
    f32x4 acc[4][4] = {};
    #pragma unroll 2
    for (int k0 = 0; k0 < Esz; k0 += 32) {
        short8 av[4], bv[4];
        #pragma unroll
        for (int mt = 0; mt < 4; ++mt) av[mt] = *(const short8*)(arow[mt] + k0);
        #pragma unroll
        for (int nt = 0; nt < 4; ++nt) bv[nt] = *(const short8*)(brow[nt] + k0);
        #pragma unroll
        for (int mt = 0; mt < 4; ++mt)
            #pragma unroll
            for (int nt = 0; nt < 4; ++nt)
                acc[mt][nt] = mfma16(av[mt], bv[nt], acc[mt][nt]);
    }
    #pragma unroll
    for (int nt = 0; nt < 4; ++nt) {
        int n = n0 + wn * 64 + nt * 16 + lr;
        float bias = b4[n];
        int g = n >> 10, j = n & 1023;
        int bk = j >> 4, jj = j & 15;
        #pragma unroll
        for (int mt = 0; mt < 4; ++mt) {
            #pragma unroll
            for (int r = 0; r < 4; ++r) {
                int b = wm * 64 + mt * 16 + lk * 4 + r;
                xp[((size_t)tp * NB + bk) * (Bsz * 64) + b * 64 + jj * 4 + g] =
                    f2bf(acc[mt][nt][r] + bias);
            }
        }
    }
}

// ---------------- fused: recurrence (blocks < NB) + next-chunk xp GEMM (blocks >= NB) ----------------
// lstm path: R11 compute with DEEPER load pipeline (4 chunks in flight: 128KB/CU
// outstanding -> Little's-law cap ~2x vs 2-deep at ~900cy MALL latency).
// gemm path: unchanged from R15.
__global__ __launch_bounds__(512, 1) void lstm_fused(
    const unsigned short* __restrict__ Wh16,
    const unsigned short* __restrict__ xpcur,   // [T'][NB][b][16][4] bf16 (read)
    unsigned short* __restrict__ xpnext,        // same layout (written by gemm path)
    const unsigned short* __restrict__ emb16,
    const unsigned short* __restrict__ Wi16,
    const float* __restrict__ b4,
    const int* __restrict__ x,
    const int* __restrict__ lengths,
    unsigned short* __restrict__ ghbuf,         // [2][64][128][16] bf16 double buffer
    float* __restrict__ cbuf,
    float* __restrict__ outh,
    unsigned* __restrict__ flags,               // [64] seqno flags, stride 32 u32
    int t0, int nsteps, int gt_base, int do_gemm)
{
    __shared__ unsigned short Whs[64][1032];   // 129 KB (forces 1 block/CU, both paths)
    __shared__ unsigned short xps[Bsz * XPS];  // 17 KB
    __shared__ unsigned short hls[Bsz * 16];   // 4 KB
    const int tid = threadIdx.x;
    const int blk = blockIdx.x;

    if (blk >= NB) {
        // ================= gemm path: xp for chunk c+1 =================
        if (!do_gemm) return;
        const int gb = blk - NB;
        const int G = (int)gridDim.x - NB;
        const int w = tid >> 6, l = tid & 63;
        const int wm = w >> 2, wn = w & 3;       // 8 waves: 2(M) x 4(N), tile 128x256
        const int lr = l & 15, lk = l >> 4;
        const int njobs = nsteps * 16;           // nsteps timesteps x 16 n-blocks(256)
        for (int job = gb; job < njobs; job += G) {
            int tp = job >> 4;
            int n0 = (job & 15) * 256;
            const unsigned short* arow[4];
            #pragma unroll
            for (int mt = 0; mt < 4; ++mt) {
                int b = wm * 64 + mt * 16 + lr;
                int xv = x[b * Tsz + gt_base + tp];
                arow[mt] = emb16 + (size_t)xv * Esz + lk * 8;
            }
            const unsigned short* brow[4];
            #pragma unroll
            for (int nt = 0; nt < 4; ++nt) {
                int n = n0 + wn * 64 + nt * 16 + lr;
                brow[nt] = Wi16 + (size_t)n * Esz + lk * 8;
            }
            f32x4 acc[4][4] = {};
            #pragma unroll 2
            for (int k0 = 0; k0 < Esz; k0 += 32) {
                short8 av[4], bv[4];
                #pragma unroll
                for (int mt = 0; mt < 4; ++mt) av[mt] = *(const short8*)(arow[mt] + k0);
                #pragma unroll
                for (int nt = 0; nt < 4; ++nt) bv[nt] = *(const short8*)(brow[nt] + k0);
                #pragma unroll
                for (int mt = 0; mt < 4; ++mt)
                    #pragma unroll
                    for (int nt = 0; nt < 4; ++nt)
                        acc[mt][nt] = mfma16(av[mt], bv[nt], acc[mt][nt]);
            }
            #pragma unroll
            for (int nt = 0; nt < 4; ++nt) {
                int n = n0 + wn * 64 + nt * 16 + lr;
                float bias = b4[n];
                int g = n >> 10, j = n & 1023;
                int bk = j >> 4, jj = j & 15;
                #pragma unroll
                for (int mt = 0; mt < 4; ++mt) {
                    #pragma unroll
                    for (int r = 0; r < 4; ++r) {
                        int b = wm * 64 + mt * 16 + lk * 4 + r;
                        xpnext[((size_t)tp * NB + bk) * (Bsz * 64) + b * 64 + jj * 4 + g] =
                            f2bf(acc[mt][nt][r] + bias);
                    }
                }
            }
        }
        return;
    }

    // ================= lstm path =================
    const int j0 = blk * 16;

    for (int idx = tid; idx < 64 * 128; idx += 512) {
        int n = idx >> 7, gq = idx & 127;
        int grow = (n >> 4) * Hsz + j0 + (n & 15);
        *(short8*)&Whs[n][gq << 3] =
            *(const short8*)(Wh16 + (size_t)grow * Hsz + gq * 8);
    }

    const int w = tid >> 6, l = tid & 63, lr = l & 15, lk = l >> 4;

    int lenr[4];
    float creg[4];
    #pragma unroll
    for (int r = 0; r < 4; ++r) {
        int b = 16 * w + 4 * lk + r;
        lenr[r] = lengths[b];
        creg[r] = cbuf[(size_t)b * Hsz + j0 + lr];
    }

    // prologue: stage xp slice for s=0
    {
        const short8* sp = (const short8*)(xpcur + (size_t)blk * (Bsz * 64));
        int xb = tid >> 2, xq = tid & 3;
        *(short8*)&xps[xb * XPS + xq * 16]     = sp[tid * 2];
        *(short8*)&xps[xb * XPS + xq * 16 + 8] = sp[tid * 2 + 1];
    }
    __syncthreads();

    const int hb_off = (lk >> 1) * 2048 + (lk & 1) * 8 + (16 * w + lr) * 16;

#define ISSUE_CHUNK(buf, kc_) do {                                         \
        GLD16C(buf[0], hb + (kc_) * 16384 + 0);                            \
        GLD16C(buf[1], hb + (kc_) * 16384 + 4096);                         \
        GLD16C(buf[2], hb + (kc_) * 16384 + 8192);                         \
        GLD16C(buf[3], hb + (kc_) * 16384 + 12288);                        \
    } while (0)

#define CONSUME(buf, kc_) do {                                             \
        _Pragma("unroll")                                                  \
        for (int ks_ = 0; ks_ < 4; ++ks_) {                                \
            short8 a_ = __builtin_bit_cast(short8, buf[ks_]);              \
            const int go_ = ((kc_) * 16 + ks_ * 4 + lk) << 3;              \
            _Pragma("unroll")                                              \
            for (int nt_ = 0; nt_ < 4; ++nt_) {                            \
                short8 bv_ = *(const short8*)&Whs[nt_ * 16 + lr][go_];     \
                acc[nt_] = mfma16(a_, bv_, acc[nt_]);                      \
            }                                                              \
        }                                                                  \
    } while (0)

    for (int s = 0; s < nsteps; ++s) {
        const int t = t0 + s;
        const unsigned short* hb = ghbuf + (size_t)(t & 1) * BH + hb_off;
        int sn = (s + 1 < nsteps) ? s + 1 : s;
        const unsigned short* xpn = xpcur + ((size_t)sn * NB + blk) * (Bsz * 64) + tid * 16;

        f32x4 acc[4] = {};
        uint4v P[4], Q[4], R[4], S[4], xr0, xr1;
        // 4-deep wait-then-consume pipeline (16 loads in flight steady-state)
        ISSUE_CHUNK(P, 0); ISSUE_CHUNK(Q, 1); ISSUE_CHUNK(R, 2); ISSUE_CHUNK(S, 3);
        WAITVM(12); CONSUME(P, 0); ISSUE_CHUNK(P, 4);
        WAITVM(12); CONSUME(Q, 1); ISSUE_CHUNK(Q, 5);
        WAITVM(12); CONSUME(R, 2); ISSUE_CHUNK(R, 6);
        WAITVM(12); CONSUME(S, 3); ISSUE_CHUNK(S, 7);
        WAITVM(12); CONSUME(P, 4);
        GLD16P(xr0, xpn); GLD16P(xr1, xpn + 8);
        WAITVM(10); CONSUME(Q, 5);
        WAITVM(6);  CONSUME(R, 6);
        WAITVM(2);  CONSUME(S, 7);             // xr may still be in flight

        #pragma unroll
        for (int r = 0; r < 4; ++r) {
            int b = 16 * w + 4 * lk + r;
            short4v xg4 = *(const short4v*)&xps[b * XPS + lr * 4];
            float zi = acc[0][r] + bf2f((unsigned short)xg4[0]);
            float zf = acc[1][r] + bf2f((unsigned short)xg4[1]);
            float zg = acc[2][r] + bf2f((unsigned short)xg4[2]);
            float zo = acc[3][r] + bf2f((unsigned short)xg4[3]);
            float it = 1.f / (1.f + __expf(-zi));
            float ft = 1.f / (1.f + __expf(-zf));
            float gt = tanhf(zg);
            float ot = 1.f / (1.f + __expf(-zo));
            float c = ft * creg[r] + it * gt;
            creg[r] = c;
            float h = ot * tanhf(c);
            if (lenr[r] == t + 1) outh[(size_t)b * Hsz + j0 + lr] = h;
            hls[b * 16 + lr] = f2bf(h);
        }
        __syncthreads();   // hls complete (all waves); xps reads for step s done

        unsigned short* ghn = ghbuf + (size_t)((t + 1) & 1) * BH;
        if (tid < 256) {
            short8 hv8 = *(const short8*)&hls[tid * 8];
            unsigned short* hd = ghn + (size_t)blk * 2048 + tid * 8;
            asm volatile("global_store_dwordx4 %0, %1, off sc0 sc1"
                         :: "v"(hd), "v"(__builtin_bit_cast(uint4v, hv8)) : "memory");
        }

        WAITVM(0);
        {
            int xb = tid >> 2, xq = tid & 3;
            *(short8*)&xps[xb * XPS + xq * 16]     = __builtin_bit_cast(short8, xr0);
            *(short8*)&xps[xb * XPS + xq * 16 + 8] = __builtin_bit_cast(short8, xr1);
        }
        __syncthreads();   // ALL threads' slab stores ACKed at MALL; xps staged

        if (tid == 0) st_flag(&flags[blk * 32], (unsigned)(t + 1));
        {
            const unsigned* fp = &flags[(tid & 63) * 32];
            while (ld_flag(fp) < (unsigned)(t + 1)) __builtin_amdgcn_s_sleep(1);
        }
        __syncthreads();
        __builtin_amdgcn_sched_barrier(0);
    }

    #pragma unroll
    for (int r = 0; r < 4; ++r) {
        int b = 16 * w + 4 * lk + r;
        cbuf[(size_t)b * Hsz + j0 + lr] = creg[r];
    }
#undef ISSUE_CHUNK
#undef CONSUME
}

// ---------------- final fc ----------------
__global__ __launch_bounds__(64) void k_fc(const float* __restrict__ outh,
                                           const float* __restrict__ fc_w,
                                           const float* __restrict__ fc_b,
                                           float* __restrict__ out) {
    int b = blockIdx.x, l = threadIdx.x;
    float s = 0.f;
    for (int k = l; k < Hsz; k += 64) s += outh[(size_t)b * Hsz + k] * fc_w[k];
    #pragma unroll
    for (int o = 32; o > 0; o >>= 1) s += __shfl_down(s, o);
    if (l == 0) out[b] = s + fc_b[0];
}

extern "C" void kernel_launch(void* const* d_in, const int* in_sizes, int n_in,
                              void* d_out, int out_size, void* d_ws, size_t ws_size,
                              hipStream_t stream) {
    const int* x       = (const int*)d_in[0];
    const int* lengths = (const int*)d_in[1];
    const float* emb   = (const float*)d_in[2];
    const float* W_ii  = (const float*)d_in[3];
    const float* W_hi  = (const float*)d_in[4];
    const float* b_i   = (const float*)d_in[5];
    const float* W_if  = (const float*)d_in[6];
    const float* W_hf  = (const float*)d_in[7];
    const float* b_f   = (const float*)d_in[8];
    const float* W_ig  = (const float*)d_in[9];
    const float* W_hg  = (const float*)d_in[10];
    const float* b_g   = (const float*)d_in[11];
    const float* W_io  = (const float*)d_in[12];
    const float* W_ho  = (const float*)d_in[13];
    const float* b_o   = (const float*)d_in[14];
    const float* fc_w  = (const float*)d_in[15];
    const float* fc_b  = (const float*)d_in[16];
    float* out = (float*)d_out;

    char* ws = (char*)d_ws;
    size_t off = 0;
    auto take = [&](size_t bytes) { size_t o = off; off += (bytes + 255) & ~(size_t)255; return o; };
    unsigned* flags       = (unsigned*)(ws + take((size_t)NB * 128));
    unsigned short* ghbuf = (unsigned short*)(ws + take((size_t)2 * BH * 2));
    float* cbuf           = (float*)(ws + take((size_t)BH * 4));
    float* outh           = (float*)(ws + take((size_t)BH * 4));
    float* b4             = (float*)(ws + take((size_t)G4H * 4));
    unsigned short* Wi16  = (unsigned short*)(ws + take((size_t)G4H * Esz * 2));
    unsigned short* Wh16  = (unsigned short*)(ws + take((size_t)G4H * Hsz * 2));
    unsigned short* emb16 = (unsigned short*)(ws + take((size_t)Vsz * Esz * 2));
    size_t fixed = off;

    int TC = 128;   // need TWO xp chunk buffers
    while (TC > 1 && fixed + 2 * ((size_t)TC * Bsz * G4H * 2 + 256) > ws_size) TC >>= 1;
    unsigned short* xp0 = (unsigned short*)(ws + take((size_t)TC * Bsz * G4H * 2));
    unsigned short* xp1 = (unsigned short*)(ws + take((size_t)TC * Bsz * G4H * 2));
    unsigned short* xpb[2] = {xp0, xp1};

    k_prep_emb<<<(Vsz * Esz + 255) / 256, 256, 0, stream>>>(emb, emb16);
    k_prep_w<<<(4 * Hsz * Esz + 255) / 256, 256, 0, stream>>>(W_ii, W_if, W_ig, W_io, Esz, Wi16);
    k_prep_w<<<(4 * Hsz * Hsz + 255) / 256, 256, 0, stream>>>(W_hi, W_hf, W_hg, W_ho, Hsz, Wh16);
    k_prep_misc<<<(2 * BH + 255) / 256, 256, 0, stream>>>(b_i, b_f, b_g, b_o, b4, ghbuf, cbuf, outh, flags);

    const int nch = Tsz / TC;
    {
        dim3 g(TC, G4H / 128);
        xp_gemm<<<g, 256, 0, stream>>>(emb16, Wi16, b4, x, xp0, 0);
    }
    for (int c = 0; c < nch; ++c) {
        lstm_fused<<<256, 512, 0, stream>>>(
            Wh16, xpb[c & 1], xpb[(c + 1) & 1], emb16, Wi16, b4, x,
            lengths, ghbuf, cbuf, outh, flags,
            c * TC, TC, (c + 1) * TC, (c + 1 < nch) ? 1 : 0);
    }
    k_fc<<<Bsz, 64, 0, stream>>>(outh, fc_w, fc_b, out);
}

// Round 17
// 3917.854 us; speedup vs baseline: 1.0174x; 1.0174x over previous
//
#include <hip/hip_runtime.h>
#include <math.h>

#define Bsz 128
#define Tsz 512
#define Esz 512
#define Hsz 1024
#define G4H 4096
#define Vsz 32000
#define NB  64           // lstm blocks (fat: 512 thr, 16 j-cols each)
#define BH  (Bsz * Hsz)

typedef __attribute__((ext_vector_type(8))) short short8;
typedef __attribute__((ext_vector_type(4))) short short4v;
typedef __attribute__((ext_vector_type(8))) __bf16 bf16x8;
typedef __attribute__((ext_vector_type(4))) float f32x4;
typedef __attribute__((ext_vector_type(4))) unsigned int uint4v;
typedef __attribute__((ext_vector_type(2))) unsigned int uint2v;

__device__ inline unsigned short f2bf(float f) {
    unsigned u = __float_as_uint(f);
    u += 0x7fffu + ((u >> 16) & 1u);   // RTNE
    return (unsigned short)(u >> 16);
}
__device__ inline float bf2f(unsigned short s) {
    return __uint_as_float(((unsigned)s) << 16);
}
__device__ inline f32x4 mfma16(short8 a, short8 b, f32x4 c) {
    return __builtin_amdgcn_mfma_f32_16x16x32_bf16(
        __builtin_bit_cast(bf16x8, a), __builtin_bit_cast(bf16x8, b), c, 0, 0, 0);
}

// async loads; early-clobber so dst never aliases addr regs
#define GLD16P(dst, p)  asm volatile("global_load_dwordx4 %0, %1, off"         : "=&v"(dst) : "v"(p))
#define GLD8P(dst, p)   asm volatile("global_load_dwordx2 %0, %1, off"         : "=&v"(dst) : "v"(p))
#define GLD16C(dst, p)  asm volatile("global_load_dwordx4 %0, %1, off sc0 sc1" : "=&v"(dst) : "v"(p))

#define WAITVM(n)                                                          \
    do { asm volatile("s_waitcnt vmcnt(" #n ")" ::: "memory");             \
         __builtin_amdgcn_sched_barrier(0); } while (0)

// MALL-coherent scalar flag ops (proven R11)
__device__ inline unsigned ld_flag(const unsigned* p) {
    unsigned r;
    asm volatile("global_load_dword %0, %1, off sc0 sc1\n\ts_waitcnt vmcnt(0)"
                 : "=&v"(r) : "v"(p) : "memory");
    return r;
}
__device__ inline void st_flag(unsigned* p, unsigned v) {
    asm volatile("global_store_dword %0, %1, off sc0 sc1" :: "v"(p), "v"(v) : "memory");
}

// ---------------- prep kernels ----------------
__global__ void k_prep_emb(const float* __restrict__ emb, unsigned short* __restrict__ dst) {
    size_t i = (size_t)blockIdx.x * 256 + threadIdx.x;
    if (i < (size_t)Vsz * Esz) dst[i] = f2bf(i < Esz ? 0.f : emb[i]);  // row 0 = PAD -> 0
}

__global__ void k_prep_w(const float* __restrict__ wi, const float* __restrict__ wf,
                         const float* __restrict__ wg, const float* __restrict__ wo,
                         int ncols, unsigned short* __restrict__ dst) {
    size_t i = (size_t)blockIdx.x * 256 + threadIdx.x;
    size_t per = (size_t)Hsz * ncols;
    if (i < 4 * per) {
        int g = (int)(i / per);
        size_t rem = i - (size_t)g * per;
        const float* src = g == 0 ? wi : g == 1 ? wf : g == 2 ? wg : wo;
        dst[i] = f2bf(src[rem]);
    }
}

__global__ void k_prep_misc(const float* __restrict__ bi, const float* __restrict__ bff,
                            const float* __restrict__ bg, const float* __restrict__ bo,
                            float* __restrict__ b4, unsigned short* __restrict__ ghbuf,
                            float* __restrict__ cbuf, float* __restrict__ outh,
                            unsigned* __restrict__ flags) {
    int i = blockIdx.x * 256 + threadIdx.x;
    if (i < G4H) {
        const float* src = i < Hsz ? bi : i < 2 * Hsz ? bff : i < 3 * Hsz ? bg : bo;
        b4[i] = src[i & (Hsz - 1)];
    }
    if (i < 2 * BH) ghbuf[i] = 0;
    if (i < BH) { cbuf[i] = 0.f; outh[i] = 0.f; }
    if (i < NB * 32) flags[i] = 0u;
}

// ---------------- xp = emb[x] @ Wi^T + b  (standalone, first-chunk prologue) ----------------
__global__ __launch_bounds__(256, 2) void xp_gemm(
    const unsigned short* __restrict__ emb16, const unsigned short* __restrict__ Wi16,
    const float* __restrict__ b4, const int* __restrict__ x,
    unsigned short* __restrict__ xp, int t_base)
{
    const int tp = blockIdx.x;
    const int n0 = blockIdx.y * 128;
    const int tid = threadIdx.x;
    const int w = tid >> 6, l = tid & 63;
    const int wm = w >> 1, wn = w & 1;
    const int lr = l & 15, lk = l >> 4;

    const unsigned short* arow[4];
    #pragma unroll
    for (int mt = 0; mt < 4; ++mt) {
        int b = wm * 64 + mt * 16 + lr;
        int xv = x[b * Tsz + t_base + tp];
        arow[mt] = emb16 + (size_t)xv * Esz + lk * 8;
    }
    const unsigned short* brow[4];
    #pragma unroll
    for (int nt = 0; nt < 4; ++nt) {
        int n = n0 + wn * 64 + nt * 16 + lr;
        brow[nt] = Wi16 + (size_t)n * Esz + lk * 8;
    }
    f32x4 acc[4][4] = {};
    #pragma unroll 2
    for (int k0 = 0; k0 < Esz; k0 += 32) {
        short8 av[4], bv[4];
        #pragma unroll
        for (int mt = 0; mt < 4; ++mt) av[mt] = *(const short8*)(arow[mt] + k0);
        #pragma unroll
        for (int nt = 0; nt < 4; ++nt) bv[nt] = *(const short8*)(brow[nt] + k0);
        #pragma unroll
        for (int mt = 0; mt < 4; ++mt)
            #pragma unroll
            for (int nt = 0; nt < 4; ++nt)
                acc[mt][nt] = mfma16(av[mt], bv[nt], acc[mt][nt]);
    }
    #pragma unroll
    for (int nt = 0; nt < 4; ++nt) {
        int n = n0 + wn * 64 + nt * 16 + lr;
        float bias = b4[n];
        int g = n >> 10, j = n & 1023;
        int bk = j >> 4, jj = j & 15;
        #pragma unroll
        for (int mt = 0; mt < 4; ++mt) {
            #pragma unroll
            for (int r = 0; r < 4; ++r) {
                int b = wm * 64 + mt * 16 + lk * 4 + r;
                xp[((size_t)tp * NB + bk) * (Bsz * 64) + b * 64 + jj * 4 + g] =
                    f2bf(acc[mt][nt][r] + bias);
            }
        }
    }
}

// ---------------- fused: recurrence (blocks < NB) + next-chunk xp GEMM (blocks >= NB) ----------------
__global__ __launch_bounds__(512, 1) void lstm_fused(
    const unsigned short* __restrict__ Wh16,
    const unsigned short* __restrict__ xpcur,   // [T'][NB][b][16][4] bf16 (read)
    unsigned short* __restrict__ xpnext,        // same layout (written by gemm path)
    const unsigned short* __restrict__ emb16,
    const unsigned short* __restrict__ Wi16,
    const float* __restrict__ b4,
    const int* __restrict__ x,
    const int* __restrict__ lengths,
    unsigned short* __restrict__ ghbuf,         // [2][64][128][16] bf16 double buffer
    float* __restrict__ cbuf,
    float* __restrict__ outh,
    unsigned* __restrict__ flags,               // [64] seqno flags, stride 32 u32
    int t0, int nsteps, int gt_base, int gn)
{
    __shared__ unsigned short Whs[64][1032];   // 129 KB (forces 1 block/CU, both paths)
    __shared__ unsigned short hls[Bsz * 16];   // 4 KB
    const int tid = threadIdx.x;
    const int blk = blockIdx.x;

    if (blk >= NB) {
        // ================= gemm path: xp for the NEXT chunk =================
        if (gn == 0) return;
        const int gb = blk - NB;
        const int G = (int)gridDim.x - NB;
        const int w = tid >> 6, l = tid & 63;
        const int wm = w >> 2, wn = w & 3;       // 8 waves: 2(M) x 4(N), tile 128x256
        const int lr = l & 15, lk = l >> 4;
        const int njobs = gn * 16;               // gn timesteps x 16 n-blocks(256)
        for (int job = gb; job < njobs; job += G) {
            int tp = job >> 4;
            int n0 = (job & 15) * 256;
            const unsigned short* arow[4];
            #pragma unroll
            for (int mt = 0; mt < 4; ++mt) {
                int b = wm * 64 + mt * 16 + lr;
                int xv = x[b * Tsz + gt_base + tp];
                arow[mt] = emb16 + (size_t)xv * Esz + lk * 8;
            }
            const unsigned short* brow[4];
            #pragma unroll
            for (int nt = 0; nt < 4; ++nt) {
                int n = n0 + wn * 64 + nt * 16 + lr;
                brow[nt] = Wi16 + (size_t)n * Esz + lk * 8;
            }
            f32x4 acc[4][4] = {};
            #pragma unroll 2
            for (int k0 = 0; k0 < Esz; k0 += 32) {
                short8 av[4], bv[4];
                #pragma unroll
                for (int mt = 0; mt < 4; ++mt) av[mt] = *(const short8*)(arow[mt] + k0);
                #pragma unroll
                for (int nt = 0; nt < 4; ++nt) bv[nt] = *(const short8*)(brow[nt] + k0);
                #pragma unroll
                for (int mt = 0; mt < 4; ++mt)
                    #pragma unroll
                    for (int nt = 0; nt < 4; ++nt)
                        acc[mt][nt] = mfma16(av[mt], bv[nt], acc[mt][nt]);
            }
            #pragma unroll
            for (int nt = 0; nt < 4; ++nt) {
                int n = n0 + wn * 64 + nt * 16 + lr;
                float bias = b4[n];
                int g = n >> 10, j = n & 1023;
                int bk = j >> 4, jj = j & 15;
                #pragma unroll
                for (int mt = 0; mt < 4; ++mt) {
                    #pragma unroll
                    for (int r = 0; r < 4; ++r) {
                        int b = wm * 64 + mt * 16 + lk * 4 + r;
                        xpnext[((size_t)tp * NB + bk) * (Bsz * 64) + b * 64 + jj * 4 + g] =
                            f2bf(acc[mt][nt][r] + bias);
                    }
                }
            }
        }
        return;
    }

    // ================= lstm path =================
    const int j0 = blk * 16;

    for (int idx = tid; idx < 64 * 128; idx += 512) {
        int n = idx >> 7, gq = idx & 127;
        int grow = (n >> 4) * Hsz + j0 + (n & 15);
        *(short8*)&Whs[n][gq << 3] =
            *(const short8*)(Wh16 + (size_t)grow * Hsz + gq * 8);
    }

    const int w = tid >> 6, l = tid & 63, lr = l & 15, lk = l >> 4;

    int lenr[4];
    float creg[4];
    #pragma unroll
    for (int r = 0; r < 4; ++r) {
        int b = 16 * w + 4 * lk + r;
        lenr[r] = lengths[b];
        creg[r] = cbuf[(size_t)b * Hsz + j0 + lr];
    }
    __syncthreads();

    const int hb_off = (lk >> 1) * 2048 + (lk & 1) * 8 + (16 * w + lr) * 16;
    // xp gate gather base for this thread (r adds 64 shorts)
    const int xg_off = (16 * w + 4 * lk) * 64 + lr * 4;

#define ISSUE_CHUNK(buf, kc_) do {                                         \
        GLD16C(buf[0], hb + (kc_) * 16384 + 0);                            \
        GLD16C(buf[1], hb + (kc_) * 16384 + 4096);                         \
        GLD16C(buf[2], hb + (kc_) * 16384 + 8192);                         \
        GLD16C(buf[3], hb + (kc_) * 16384 + 12288);                        \
    } while (0)

#define CONSUME(buf, kc_) do {                                             \
        _Pragma("unroll")                                                  \
        for (int ks_ = 0; ks_ < 4; ++ks_) {                                \
            short8 a_ = __builtin_bit_cast(short8, buf[ks_]);              \
            const int go_ = ((kc_) * 16 + ks_ * 4 + lk) << 3;              \
            _Pragma("unroll")                                              \
            for (int nt_ = 0; nt_ < 4; ++nt_) {                            \
                short8 bv_ = *(const short8*)&Whs[nt_ * 16 + lr][go_];     \
                acc[nt_] = mfma16(a_, bv_, acc[nt_]);                      \
            }                                                              \
        }                                                                  \
    } while (0)

    for (int s = 0; s < nsteps; ++s) {
        const int t = t0 + s;
        const unsigned short* hb = ghbuf + (size_t)(t & 1) * BH + hb_off;
        const unsigned short* xgp = xpcur + (size_t)s * (NB * Bsz * 64)
                                  + (size_t)blk * (Bsz * 64) + xg_off;

        // per-thread gate-addend gather (cached; retires with first counted wait)
        uint2v xg[4];
        GLD8P(xg[0], xgp + 0);
        GLD8P(xg[1], xgp + 64);
        GLD8P(xg[2], xgp + 128);
        GLD8P(xg[3], xgp + 192);

        f32x4 acc[4] = {};
        uint4v P[4], Q[4], R[4], S[4];
        // 4-deep wait-then-consume pipeline (xg issued first: 20 outstanding at
        // first wait -> WAITVM(12) retires xg + chunk0)
        ISSUE_CHUNK(P, 0); ISSUE_CHUNK(Q, 1); ISSUE_CHUNK(R, 2); ISSUE_CHUNK(S, 3);
        WAITVM(12); CONSUME(P, 0); ISSUE_CHUNK(P, 4);
        WAITVM(12); CONSUME(Q, 1); ISSUE_CHUNK(Q, 5);
        WAITVM(12); CONSUME(R, 2); ISSUE_CHUNK(R, 6);
        WAITVM(12); CONSUME(S, 3); ISSUE_CHUNK(S, 7);
        WAITVM(12); CONSUME(P, 4);
        WAITVM(8);  CONSUME(Q, 5);
        WAITVM(4);  CONSUME(R, 6);
        WAITVM(0);  CONSUME(S, 7);

        // gates: lane owns (b=16w+4lk+r, j=j0+lr); all 4 gates in acc[nt][r];
        // xp addend from registers
        #pragma unroll
        for (int r = 0; r < 4; ++r) {
            int b = 16 * w + 4 * lk + r;
            short4v xg4 = __builtin_bit_cast(short4v, xg[r]);
            float zi = acc[0][r] + bf2f((unsigned short)xg4[0]);
            float zf = acc[1][r] + bf2f((unsigned short)xg4[1]);
            float zg = acc[2][r] + bf2f((unsigned short)xg4[2]);
            float zo = acc[3][r] + bf2f((unsigned short)xg4[3]);
            float it = 1.f / (1.f + __expf(-zi));
            float ft = 1.f / (1.f + __expf(-zf));
            float gt = tanhf(zg);
            float ot = 1.f / (1.f + __expf(-zo));
            float c = ft * creg[r] + it * gt;
            creg[r] = c;
            float h = ot * tanhf(c);
            if (lenr[r] == t + 1) outh[(size_t)b * Hsz + j0 + lr] = h;
            hls[b * 16 + lr] = f2bf(h);
        }
        __syncthreads();   // hls complete (all waves)

        // coalesced h slab store: one contiguous 4KB burst, write-through to MALL
        unsigned short* ghn = ghbuf + (size_t)((t + 1) & 1) * BH;
        if (tid < 256) {
            short8 hv8 = *(const short8*)&hls[tid * 8];
            unsigned short* hd = ghn + (size_t)blk * 2048 + tid * 8;
            asm volatile("global_store_dwordx4 %0, %1, off sc0 sc1"
                         :: "v"(hd), "v"(__builtin_bit_cast(uint4v, hv8)) : "memory");
        }
        WAITVM(0);         // slab stores ACKed at MALL
        __syncthreads();

        // ---- decentralized sync: tid0 posts, wave 0 polls all 64 flags ----
        if (tid == 0) st_flag(&flags[blk * 32], (unsigned)(t + 1));
        if (tid < 64) {
            const unsigned* fp = &flags[tid * 32];
            unsigned tgt = (unsigned)(t + 1);
            unsigned v = ld_flag(fp);
            while (!__all((int)(v >= tgt))) {
                __builtin_amdgcn_s_sleep(1);
                v = ld_flag(fp);
            }
        }
        __syncthreads();
        __builtin_amdgcn_sched_barrier(0);   // keep next-step loads below the sync
    }

    #pragma unroll
    for (int r = 0; r < 4; ++r) {
        int b = 16 * w + 4 * lk + r;
        cbuf[(size_t)b * Hsz + j0 + lr] = creg[r];
    }
#undef ISSUE_CHUNK
#undef CONSUME
}

// ---------------- final fc ----------------
__global__ __launch_bounds__(64) void k_fc(const float* __restrict__ outh,
                                           const float* __restrict__ fc_w,
                                           const float* __restrict__ fc_b,
                                           float* __restrict__ out) {
    int b = blockIdx.x, l = threadIdx.x;
    float s = 0.f;
    for (int k = l; k < Hsz; k += 64) s += outh[(size_t)b * Hsz + k] * fc_w[k];
    #pragma unroll
    for (int o = 32; o > 0; o >>= 1) s += __shfl_down(s, o);
    if (l == 0) out[b] = s + fc_b[0];
}

extern "C" void kernel_launch(void* const* d_in, const int* in_sizes, int n_in,
                              void* d_out, int out_size, void* d_ws, size_t ws_size,
                              hipStream_t stream) {
    const int* x       = (const int*)d_in[0];
    const int* lengths = (const int*)d_in[1];
    const float* emb   = (const float*)d_in[2];
    const float* W_ii  = (const float*)d_in[3];
    const float* W_hi  = (const float*)d_in[4];
    const float* b_i   = (const float*)d_in[5];
    const float* W_if  = (const float*)d_in[6];
    const float* W_hf  = (const float*)d_in[7];
    const float* b_f   = (const float*)d_in[8];
    const float* W_ig  = (const float*)d_in[9];
    const float* W_hg  = (const float*)d_in[10];
    const float* b_g   = (const float*)d_in[11];
    const float* W_io  = (const float*)d_in[12];
    const float* W_ho  = (const float*)d_in[13];
    const float* b_o   = (const float*)d_in[14];
    const float* fc_w  = (const float*)d_in[15];
    const float* fc_b  = (const float*)d_in[16];
    float* out = (float*)d_out;

    char* ws = (char*)d_ws;
    size_t off = 0;
    auto take = [&](size_t bytes) { size_t o = off; off += (bytes + 255) & ~(size_t)255; return o; };
    unsigned* flags       = (unsigned*)(ws + take((size_t)NB * 128));
    unsigned short* ghbuf = (unsigned short*)(ws + take((size_t)2 * BH * 2));
    float* cbuf           = (float*)(ws + take((size_t)BH * 4));
    float* outh           = (float*)(ws + take((size_t)BH * 4));
    float* b4             = (float*)(ws + take((size_t)G4H * 4));
    unsigned short* Wi16  = (unsigned short*)(ws + take((size_t)G4H * Esz * 2));
    unsigned short* Wh16  = (unsigned short*)(ws + take((size_t)G4H * Hsz * 2));
    unsigned short* emb16 = (unsigned short*)(ws + take((size_t)Vsz * Esz * 2));

    // two xp chunk buffers, capacity 64 steps each (proven fit at R15/R16)
    const int TCcap = 64;
    unsigned short* xp0 = (unsigned short*)(ws + take((size_t)TCcap * Bsz * G4H * 2));
    unsigned short* xp1 = (unsigned short*)(ws + take((size_t)TCcap * Bsz * G4H * 2));
    unsigned short* xpb[2] = {xp0, xp1};

    k_prep_emb<<<(Vsz * Esz + 255) / 256, 256, 0, stream>>>(emb, emb16);
    k_prep_w<<<(4 * Hsz * Esz + 255) / 256, 256, 0, stream>>>(W_ii, W_if, W_ig, W_io, Esz, Wi16);
    k_prep_w<<<(4 * Hsz * Hsz + 255) / 256, 256, 0, stream>>>(W_hi, W_hf, W_hg, W_ho, Hsz, Wh16);
    k_prep_misc<<<(2 * BH + 255) / 256, 256, 0, stream>>>(b_i, b_f, b_g, b_o, b4, ghbuf, cbuf, outh, flags);

    // chunk plan: serial prologue covers only [0,16); sizes ramp 16,32 then 64s
    // so each dispatch's gemm path (next chunk) fits under its lstm long pole.
    const int bounds[11] = {0, 16, 48, 112, 176, 240, 304, 368, 432, 496, 512};
    const int nch = 10;

    {   // serial prologue: xp for chunk 0 ([0,16))
        dim3 g(bounds[1], 32);
        xp_gemm<<<g, 256, 0, stream>>>(emb16, Wi16, b4, x, xp0, 0);
    }
    for (int i = 0; i < nch; ++i) {
        int t0b = bounds[i], ns = bounds[i + 1] - bounds[i];
        int gtb = bounds[i + 1];
        int gn = (i + 1 < nch) ? bounds[i + 2] - bounds[i + 1] : 0;
        lstm_fused<<<256, 512, 0, stream>>>(
            Wh16, xpb[i & 1], xpb[(i + 1) & 1], emb16, Wi16, b4, x,
            lengths, ghbuf, cbuf, outh, flags,
            t0b, ns, gtb, gn);
    }
    k_fc<<<Bsz, 64, 0, stream>>>(outh, fc_w, fc_b, out);
}